// Round 11
// baseline (1504.869 us; speedup 1.0000x reference)
//
#include <hip/hip_runtime.h>
#include <cstdint>
#include <cstddef>

#define IN_C 128
#define HIDc 128
#define OUTc 64

using bf8 = __attribute__((ext_vector_type(8))) __bf16;
using f4  = __attribute__((ext_vector_type(4))) float;

// ---- bf16 helpers (RNE) ----
__device__ __forceinline__ unsigned short f2bf(float f) {
    unsigned int u = __float_as_uint(f);
    unsigned int r = (u + 0x7FFFu + ((u >> 16) & 1u)) >> 16;
    return (unsigned short)r;
}
__device__ __forceinline__ float bf2f(unsigned short h) {
    return __uint_as_float(((unsigned int)h) << 16);
}

// ---------------------------------------------------------------------------
// Graph build (battle-tested r3-r10).
// ---------------------------------------------------------------------------
__global__ void k_detect(const long long* ei, int n_nodes, int* flag) {
    int t = threadIdx.x;                    // blockDim = 64
    long long v = ei[t];
    int ok = (v >= 0 && v < (long long)n_nodes) ? 1 : 0;
    unsigned long long m = __ballot(ok);
    if (t == 0) *flag = (m == ~0ull) ? 1 : 0;
}

__global__ void k_cvt_hist(const void* ei, int twoE, int E, const int* flag,
                           int* __restrict__ out, int* __restrict__ deg, int n) {
    int i = blockIdx.x * blockDim.x + threadIdx.x;
    if (i >= twoE) return;
    int v = (*flag) ? (int)((const long long*)ei)[i] : ((const int*)ei)[i];
    out[i] = v;
    if (i >= E && (unsigned)v < (unsigned)n) atomicAdd(&deg[v], 1);
}

__global__ void k_dinv(const int* __restrict__ deg, float* __restrict__ dinv, int n) {
    int i = blockIdx.x * blockDim.x + threadIdx.x;
    if (i < n) dinv[i] = (deg[i] > 0) ? rsqrtf((float)deg[i]) : 0.0f;
}

__global__ void k_alloc(const int* __restrict__ deg, int* __restrict__ base,
                        int* __restrict__ cursor, int* __restrict__ counter, int n) {
    int i = blockIdx.x * blockDim.x + threadIdx.x;
    int lane = threadIdx.x & 63;
    int val = (i < n) ? deg[i] : 0;
    int scan = val;
    #pragma unroll
    for (int off = 1; off < 64; off <<= 1) {
        int t = __shfl_up(scan, off);
        if (lane >= off) scan += t;
    }
    int excl = scan - val;
    int total = __shfl(scan, 63);
    int wb = 0;
    if (lane == 0) wb = atomicAdd(counter, total);
    wb = __shfl(wb, 0);
    if (i < n) { base[i] = wb + excl; cursor[i] = wb + excl; }
}

__global__ void k_scatter(const int* __restrict__ eint, int E,
                          const float* __restrict__ dinv, int n,
                          int* __restrict__ cursor, int2* __restrict__ ew) {
    int e = blockIdx.x * blockDim.x + threadIdx.x;
    if (e >= E) return;
    int r = eint[e];
    int c = eint[E + e];
    if ((unsigned)r >= (unsigned)n || (unsigned)c >= (unsigned)n) return;
    int p = atomicAdd(&cursor[c], 1);
    int2 v; v.x = r; v.y = __float_as_int(dinv[r] * dinv[c]);
    ew[p] = v;
}

// ---------------------------------------------------------------------------
// Weight prep: W (nstack, K, N) fp32 -> Wt (nstack*N rows, K) bf16 (transposed).
// ---------------------------------------------------------------------------
__global__ void k_wprep(const float* __restrict__ W, unsigned short* __restrict__ Wt,
                        int K, int N) {
    int j = blockIdx.y;
    int idx = blockIdx.x * 256 + threadIdx.x;
    if (idx >= K * N) return;
    int k = idx / N, nn = idx - k * N;
    Wt[(size_t)j * N * K + (size_t)nn * K + k] = f2bf(W[(size_t)j * K * N + idx]);
}

__global__ void k_cast4(const float* __restrict__ x, unsigned short* __restrict__ y, int n4) {
    int i = blockIdx.x * 256 + threadIdx.x;
    if (i >= n4) return;
    float4 v = ((const float4*)x)[i];
    ushort4 o;
    o.x = f2bf(v.x); o.y = f2bf(v.y); o.z = f2bf(v.z); o.w = f2bf(v.w);
    ((ushort4*)y)[i] = o;
}

// ---------------------------------------------------------------------------
// LDS-staged fused MFMA GEMM (r10 lesson: LDS-free per-lane fragment loads
// hit 16 scattered cache lines per instruction -> transaction-bound, MfmaUtil
// stuck at ~6.8% across 3 structures. Fix: coalesced uint4 global loads ->
// LDS (stride-40 pad: staging writes 2-way aliased = free, fragment
// ds_read_b128 conflict-free), then LDS fragment reads).
//   C (M x NT, pieces of width PW) = concat(A0,A1,A2)(M x K) @ Bt^T + bias
// Tile: 64 rows x NT cols, BK=32, 256 thr / 4 waves (wave = NT/4 col strip).
// acc = 4 x (NT/64) f4 <= 96 VGPR -> ~3 blocks/CU for barrier overlap.
// ---------------------------------------------------------------------------
template<int PW, int NT, bool BFOUT>
__global__ __launch_bounds__(256) void k_gemm(
    const unsigned short* __restrict__ A0, const unsigned short* __restrict__ A1,
    const unsigned short* __restrict__ A2, int W, int M, int K,
    const unsigned short* __restrict__ Bt,   // NT rows x K, bf16
    const float* __restrict__ bias,          // NT
    unsigned short* __restrict__ C0, unsigned short* __restrict__ C1,
    unsigned short* __restrict__ C2, float* __restrict__ Cf)
{
    constexpr int TN = NT / 64;              // frags per wave: 6 / 3 / 1
    __shared__ __align__(16) unsigned short As[64 * 40];
    __shared__ __align__(16) unsigned short Bs[NT * 40];

    int t = threadIdx.x;
    int wave = t >> 6, lane = t & 63;
    int m16 = lane & 15, q = lane >> 4;
    int row0 = blockIdx.x * 64;
    int wc = wave * (NT / 4);

    int srow = t >> 2, sch = t & 3;          // staging: 64 rows x 4 chunks(16B)
    int arow = row0 + srow; if (arow >= M) arow = M - 1;   // clamp, stores guarded

    f4 acc[4][TN];
    #pragma unroll
    for (int i = 0; i < 4; i++)
        #pragma unroll
        for (int j = 0; j < TN; j++) acc[i][j] = (f4){0.f, 0.f, 0.f, 0.f};

    for (int kk = 0; kk < K; kk += 32) {
        int pi = kk / W;
        const unsigned short* Ap = (pi == 0) ? A0 : ((pi == 1) ? A1 : A2);
        int kl = kk - pi * W;                // piece-local k: A only (B uses kk)

        uint4 av = *(const uint4*)&Ap[(size_t)arow * W + kl + sch * 8];
        uint4 bv[TN];
        #pragma unroll
        for (int i = 0; i < TN; i++) {
            int u = t + i * 256;
            int br = u >> 2, bc = u & 3;
            bv[i] = *(const uint4*)&Bt[(size_t)br * K + kk + bc * 8];
        }
        __syncthreads();
        *(uint4*)&As[srow * 40 + sch * 8] = av;
        #pragma unroll
        for (int i = 0; i < TN; i++) {
            int u = t + i * 256;
            int br = u >> 2, bc = u & 3;
            *(uint4*)&Bs[br * 40 + bc * 8] = bv[i];
        }
        __syncthreads();

        bf8 af[4], bfr[TN];
        #pragma unroll
        for (int tm = 0; tm < 4; tm++)
            af[tm] = *(const bf8*)&As[(tm * 16 + m16) * 40 + q * 8];
        #pragma unroll
        for (int tn = 0; tn < TN; tn++)
            bfr[tn] = *(const bf8*)&Bs[(wc + tn * 16 + m16) * 40 + q * 8];
        #pragma unroll
        for (int tm = 0; tm < 4; tm++)
            #pragma unroll
            for (int tn = 0; tn < TN; tn++)
                acc[tm][tn] = __builtin_amdgcn_mfma_f32_16x16x32_bf16(
                    af[tm], bfr[tn], acc[tm][tn], 0, 0, 0);
    }

    #pragma unroll
    for (int tn = 0; tn < TN; tn++) {
        int col_base = wc + tn * 16;         // global col in NT; 16-frag never crosses PW
        int j  = col_base / PW;
        int cc = col_base - j * PW + m16;
        unsigned short* Cj = (j == 0) ? C0 : ((j == 1) ? C1 : C2);
        float bi = bias[col_base + m16];
        #pragma unroll
        for (int tm = 0; tm < 4; tm++) {
            #pragma unroll
            for (int r = 0; r < 4; r++) {
                int row = row0 + tm * 16 + q * 4 + r;
                if (row >= M) continue;
                float v = acc[tm][tn][r] + bi;
                if (BFOUT) Cj[(size_t)row * PW + cc] = f2bf(v);
                else       Cf[(size_t)row * PW + cc] = v;
            }
        }
    }
}

// ---------------------------------------------------------------------------
// SpMM (bf16 in/out, fp32 accumulate), packed edges, unroll-8.
// ---------------------------------------------------------------------------
template<int V, bool DUAL>
__global__ __launch_bounds__(256) void k_spmm(
    const unsigned short* __restrict__ S1, const unsigned short* __restrict__ S2,
    unsigned short* __restrict__ D1, unsigned short* __restrict__ D2, int width,
    const int* __restrict__ base, const int* __restrict__ deg,
    const int2* __restrict__ ew, int n)
{
    int node = blockIdx.x * 4 + threadIdx.y;
    if (node >= n) return;
    int tx = threadIdx.x;
    float a1[V], a2[V];
    #pragma unroll
    for (int v = 0; v < V; v++) { a1[v] = 0.f; if (DUAL) a2[v] = 0.f; }
    int b = base[node], end = b + deg[node];
    const unsigned short* P1 = S1 + tx * V;
    const unsigned short* P2 = DUAL ? (S2 + tx * V) : nullptr;
    constexpr int UN = 8;
    int e = b;
    for (; e + UN <= end; e += UN) {
        int2 ev[UN];
        #pragma unroll
        for (int u = 0; u < UN; u++) ev[u] = ew[e + u];
        unsigned int g1[UN], g2[UN];
        #pragma unroll
        for (int u = 0; u < UN; u++) {
            if (V == 2) g1[u] = *(const unsigned int*)(P1 + (size_t)ev[u].x * width);
            else        g1[u] = P1[(size_t)ev[u].x * width];
            if (DUAL) {
                if (V == 2) g2[u] = *(const unsigned int*)(P2 + (size_t)ev[u].x * width);
                else        g2[u] = P2[(size_t)ev[u].x * width];
            }
        }
        #pragma unroll
        for (int u = 0; u < UN; u++) {
            float we = __int_as_float(ev[u].y);
            if (V == 2) {
                a1[0] += we * bf2f((unsigned short)(g1[u] & 0xffff));
                a1[1] += we * bf2f((unsigned short)(g1[u] >> 16));
                if (DUAL) {
                    a2[0] += we * bf2f((unsigned short)(g2[u] & 0xffff));
                    a2[1] += we * bf2f((unsigned short)(g2[u] >> 16));
                }
            } else {
                a1[0] += we * bf2f((unsigned short)g1[u]);
                if (DUAL) a2[0] += we * bf2f((unsigned short)g2[u]);
            }
        }
    }
    for (; e < end; ++e) {
        int2 ev = ew[e];
        float we = __int_as_float(ev.y);
        if (V == 2) {
            unsigned int u1 = *(const unsigned int*)(P1 + (size_t)ev.x * width);
            a1[0] += we * bf2f((unsigned short)(u1 & 0xffff));
            a1[1] += we * bf2f((unsigned short)(u1 >> 16));
            if (DUAL) {
                unsigned int u2 = *(const unsigned int*)(P2 + (size_t)ev.x * width);
                a2[0] += we * bf2f((unsigned short)(u2 & 0xffff));
                a2[1] += we * bf2f((unsigned short)(u2 >> 16));
            }
        } else {
            a1[0] += we * bf2f(P1[(size_t)ev.x * width]);
            if (DUAL) a2[0] += we * bf2f(P2[(size_t)ev.x * width]);
        }
    }
    size_t o = (size_t)node * width + tx * V;
    if (V == 2) {
        ushort2 o1; o1.x = f2bf(a1[0]); o1.y = f2bf(a1[1]);
        *(ushort2*)&D1[o] = o1;
        if (DUAL) { ushort2 o2; o2.x = f2bf(a2[0]); o2.y = f2bf(a2[1]);
                    *(ushort2*)&D2[o] = o2; }
    } else {
        D1[o] = f2bf(a1[0]);
        if (DUAL) D2[o] = f2bf(a2[0]);
    }
}

// ---------------------------------------------------------------------------
// BatchNorm: stats + finalize + in-place apply (bf16, battle-tested r5).
// ---------------------------------------------------------------------------
__global__ void k_bnstats(const unsigned short* __restrict__ p0,
                          const unsigned short* __restrict__ p1,
                          const unsigned short* __restrict__ p2,
                          float* __restrict__ sums, float* __restrict__ sumsq, int n)
{
    int c = threadIdx.x;
    int cc = c & 127;
    int pi = c >> 7;
    const unsigned short* src = (pi == 0) ? p0 : ((pi == 1) ? p1 : p2);
    float s = 0.f, s2 = 0.f;
    for (int r = blockIdx.x; r < n; r += gridDim.x) {
        float v = bf2f(src[(size_t)r * 128 + cc]);
        s += v; s2 += v * v;
    }
    atomicAdd(&sums[c], s);
    atomicAdd(&sumsq[c], s2);
}

__global__ void k_bnfin(const float* __restrict__ sums, const float* __restrict__ sumsq,
                        const float* __restrict__ g, const float* __restrict__ bb,
                        float* __restrict__ scale, float* __restrict__ shift,
                        int cat, float invn)
{
    int c = threadIdx.x;
    if (c >= cat) return;
    float mu  = sums[c] * invn;
    float var = sumsq[c] * invn - mu * mu;
    float sc  = g[c] * rsqrtf(var + 1e-5f);
    scale[c] = sc;
    shift[c] = bb[c] - mu * sc;
}

__global__ void k_bnapply(unsigned short* __restrict__ p0, unsigned short* __restrict__ p1,
                          unsigned short* __restrict__ p2,
                          const float* __restrict__ scale, const float* __restrict__ shift,
                          int n)
{
    int c = threadIdx.x;              // 384
    int cc = c & 127;
    int pi = c >> 7;
    unsigned short* src = (pi == 0) ? p0 : ((pi == 1) ? p1 : p2);
    float sc = scale[c], sh = shift[c];
    for (int r = blockIdx.x; r < n; r += gridDim.x) {
        size_t idx = (size_t)r * 128 + cc;
        float v = bf2f(src[idx]) * sc + sh;
        src[idx] = f2bf(fmaxf(v, 0.0f));
    }
}

// Diagnostic: if workspace is too small, surface ws_size (MB) via d_out.
__global__ void k_diag(float* out, float val, int n) {
    int i = blockIdx.x * blockDim.x + threadIdx.x;
    if (i < n) out[i] = val;
}

// ---------------------------------------------------------------------------
extern "C" void kernel_launch(void* const* d_in, const int* in_sizes, int n_in,
                              void* d_out, int out_size, void* d_ws, size_t ws_size,
                              hipStream_t stream)
{
    const float* x    = (const float*)d_in[0];
    const void*  ei   = d_in[1];
    const float* W0   = (const float*)d_in[2];
    const float* b0   = (const float*)d_in[3];
    const float* W1   = (const float*)d_in[4];
    const float* b1   = (const float*)d_in[5];
    const float* W2   = (const float*)d_in[6];
    const float* b2   = (const float*)d_in[7];
    const float* bn0g = (const float*)d_in[8];
    const float* bn0b = (const float*)d_in[9];
    const float* bn1g = (const float*)d_in[10];
    const float* bn1b = (const float*)d_in[11];
    const float* fpW  = (const float*)d_in[12];
    const float* fpb  = (const float*)d_in[13];
    float* out = (float*)d_out;

    const int N    = in_sizes[0] / IN_C;
    const int twoE = in_sizes[1];
    const int E    = twoE / 2;

    // ---- workspace carve (~184 MB; budget 256 MiB) ----
    char* p = (char*)d_ws;
    auto alloc = [&](size_t bytes) -> char* {
        char* r = p; p += (bytes + 255) & ~(size_t)255; return r;
    };
    unsigned short* U[6];
    for (int i = 0; i < 6; i++) U[i] = (unsigned short*)alloc((size_t)N * 128 * 2);
    unsigned short* Wt0 = (unsigned short*)alloc((size_t)3 * 128 * 128 * 2);
    unsigned short* Wt1 = (unsigned short*)alloc((size_t)3 * 384 * 128 * 2);
    unsigned short* Wt2 = (unsigned short*)alloc((size_t)3 * 384 * 64 * 2);
    unsigned short* WtF = (unsigned short*)alloc((size_t)192 * 64 * 2);
    float* dinv  = (float*)alloc((size_t)N * 4);
    int2*  ew    = (int2*)alloc((size_t)E * 8);
    float* sums  = (float*)alloc(2 * 384 * 4);
    float* sumsq = sums + 384;
    float* scale = (float*)alloc(384 * 4);
    float* shift = (float*)alloc(384 * 4);
    int* deg     = (int*)alloc((size_t)N * 4);
    int* base    = (int*)alloc((size_t)N * 4);
    int* cursor  = (int*)alloc((size_t)N * 4);
    int* eint    = (int*)alloc((size_t)twoE * 4);
    int* counter = (int*)alloc(4);
    int* flag    = (int*)alloc(4);

    size_t required = (size_t)(p - (char*)d_ws);
    if (required > ws_size) {
        k_diag<<<(out_size + 255) / 256, 256, 0, stream>>>(
            out, (float)(ws_size >> 20), out_size);
        return;
    }

    const int T = 256;
    dim3 spmm_blk(64, 4);
    int  spmm_grid = (N + 3) / 4;
    int  gx64 = (N + 63) / 64;

    // ---- weight prep + input cast ----
    k_wprep<<<dim3((128 * 128 + 255) / 256, 3), T, 0, stream>>>(W0, Wt0, 128, 128);
    k_wprep<<<dim3((384 * 128 + 255) / 256, 3), T, 0, stream>>>(W1, Wt1, 384, 128);
    k_wprep<<<dim3((384 * 64  + 255) / 256, 3), T, 0, stream>>>(W2, Wt2, 384, 64);
    k_wprep<<<dim3((192 * 64  + 255) / 256, 1), T, 0, stream>>>(fpW, WtF, 192, 64);
    unsigned short* Xb = U[3];
    k_cast4<<<((N * 128 / 4) + 255) / 256, T, 0, stream>>>(x, Xb, N * 128 / 4);

    // ---- graph build ----
    hipMemsetAsync(deg, 0, (size_t)N * 4, stream);
    hipMemsetAsync(counter, 0, 4, stream);
    k_detect<<<1, 64, 0, stream>>>((const long long*)ei, N, flag);
    k_cvt_hist<<<(twoE + T - 1) / T, T, 0, stream>>>(ei, twoE, E, flag, eint, deg, N);
    k_dinv<<<(N + T - 1) / T, T, 0, stream>>>(deg, dinv, N);
    k_alloc<<<(N + T - 1) / T, T, 0, stream>>>(deg, base, cursor, counter, N);
    k_scatter<<<(E + T - 1) / T, T, 0, stream>>>(eint, E, dinv, N, cursor, ew);

    // ---- layer 0: Xb(=U3) -> G0:U0, G1:U1, G2:U2 ----
    k_gemm<128, 384, true><<<gx64, T, 0, stream>>>(Xb, Xb, Xb, 128, N, 128,
        Wt0, b0, U[0], U[1], U[2], nullptr);
    // H1 = A*G1 -> U4 ; T = A*G2 -> U5 ; H2 = A*T -> U3
    k_spmm<2, true ><<<spmm_grid, spmm_blk, 0, stream>>>(U[1], U[2], U[4], U[5], 128,
                                                         base, deg, ew, N);
    k_spmm<2, false><<<spmm_grid, spmm_blk, 0, stream>>>(U[5], nullptr, U[3], nullptr, 128,
                                                         base, deg, ew, N);
    hipMemsetAsync(sums, 0, 2 * 384 * 4, stream);
    k_bnstats<<<2048, 384, 0, stream>>>(U[0], U[4], U[3], sums, sumsq, N);
    k_bnfin<<<1, 384, 0, stream>>>(sums, sumsq, bn0g, bn0b, scale, shift, 384, 1.0f / N);
    k_bnapply<<<2048, 384, 0, stream>>>(U[0], U[4], U[3], scale, shift, N);
    // layer-0 output (post BN+ReLU, in place): (U0, U4, U3)

    // ---- layer 1: (U0,U4,U3) -> G0:U1, G1:U2, G2:U5 ----
    k_gemm<128, 384, true><<<gx64, T, 0, stream>>>(U[0], U[4], U[3], 128, N, 384,
        Wt1, b1, U[1], U[2], U[5], nullptr);
    // H1 = A*G1 -> U0 ; T = A*G2 -> U4 ; H2 = A*T -> U3
    k_spmm<2, true ><<<spmm_grid, spmm_blk, 0, stream>>>(U[2], U[5], U[0], U[4], 128,
                                                         base, deg, ew, N);
    k_spmm<2, false><<<spmm_grid, spmm_blk, 0, stream>>>(U[4], nullptr, U[3], nullptr, 128,
                                                         base, deg, ew, N);
    hipMemsetAsync(sums, 0, 2 * 384 * 4, stream);
    k_bnstats<<<2048, 384, 0, stream>>>(U[1], U[0], U[3], sums, sumsq, N);
    k_bnfin<<<1, 384, 0, stream>>>(sums, sumsq, bn1g, bn1b, scale, shift, 384, 1.0f / N);
    k_bnapply<<<2048, 384, 0, stream>>>(U[1], U[0], U[3], scale, shift, N);
    // layer-1 output: (U1, U0, U3)

    // ---- layer 2: (U1,U0,U3) -> 64-wide pieces in halves of U2/U4/U5 ----
    unsigned short* V2a = U[2];
    unsigned short* V2b = U[2] + (size_t)N * 64;
    unsigned short* V4a = U[4];
    unsigned short* V4b = U[4] + (size_t)N * 64;
    unsigned short* V5a = U[5];
    unsigned short* V5b = U[5] + (size_t)N * 64;
    k_gemm<64, 192, true><<<gx64, T, 0, stream>>>(U[1], U[0], U[3], 128, N, 384,
        Wt2, b2, V2a, V2b, V4a, nullptr);
    // A*L1(V2b) -> V4b ; T = A*L2(V4a) -> V5a ; A*T -> V5b
    k_spmm<1, true ><<<spmm_grid, spmm_blk, 0, stream>>>(V2b, V4a, V4b, V5a, 64,
                                                         base, deg, ew, N);
    k_spmm<1, false><<<spmm_grid, spmm_blk, 0, stream>>>(V5a, nullptr, V5b, nullptr, 64,
                                                         base, deg, ew, N);

    // ---- final projection: out = concat(V2a, V4b, V5b)(N x 192) @ fpW + fpb ----
    k_gemm<64, 64, false><<<gx64, T, 0, stream>>>(V2a, V4b, V5b, 64, N, 192,
        WtF, fpb, nullptr, nullptr, nullptr, out);
}

// Round 12
// 1314.235 us; speedup vs baseline: 1.1451x; 1.1451x over previous
//
#include <hip/hip_runtime.h>
#include <cstdint>
#include <cstddef>

#define IN_C 128
#define HIDc 128
#define OUTc 64

using bf8 = __attribute__((ext_vector_type(8))) __bf16;
using f4  = __attribute__((ext_vector_type(4))) float;

// ---- bf16 helpers (RNE) ----
__device__ __forceinline__ unsigned short f2bf(float f) {
    unsigned int u = __float_as_uint(f);
    unsigned int r = (u + 0x7FFFu + ((u >> 16) & 1u)) >> 16;
    return (unsigned short)r;
}
__device__ __forceinline__ float bf2f(unsigned short h) {
    return __uint_as_float(((unsigned int)h) << 16);
}

// Async global->LDS, 16 B per lane. LDS dest is the WAVE-UNIFORM base; HW
// scatters lane i's 16 B to base + i*16 (guide §5, m97/m104).
__device__ __forceinline__ void gload16(const unsigned short* g, unsigned short* l) {
    __builtin_amdgcn_global_load_lds(
        (const __attribute__((address_space(1))) unsigned int*)g,
        (__attribute__((address_space(3))) unsigned int*)l, 16, 0, 0);
}

// ---------------------------------------------------------------------------
// Graph build (battle-tested r3-r11).
// ---------------------------------------------------------------------------
__global__ void k_detect(const long long* ei, int n_nodes, int* flag) {
    int t = threadIdx.x;                    // blockDim = 64
    long long v = ei[t];
    int ok = (v >= 0 && v < (long long)n_nodes) ? 1 : 0;
    unsigned long long m = __ballot(ok);
    if (t == 0) *flag = (m == ~0ull) ? 1 : 0;
}

__global__ void k_cvt_hist(const void* ei, int twoE, int E, const int* flag,
                           int* __restrict__ out, int* __restrict__ deg, int n) {
    int i = blockIdx.x * blockDim.x + threadIdx.x;
    if (i >= twoE) return;
    int v = (*flag) ? (int)((const long long*)ei)[i] : ((const int*)ei)[i];
    out[i] = v;
    if (i >= E && (unsigned)v < (unsigned)n) atomicAdd(&deg[v], 1);
}

__global__ void k_dinv(const int* __restrict__ deg, float* __restrict__ dinv, int n) {
    int i = blockIdx.x * blockDim.x + threadIdx.x;
    if (i < n) dinv[i] = (deg[i] > 0) ? rsqrtf((float)deg[i]) : 0.0f;
}

__global__ void k_alloc(const int* __restrict__ deg, int* __restrict__ base,
                        int* __restrict__ cursor, int* __restrict__ counter, int n) {
    int i = blockIdx.x * blockDim.x + threadIdx.x;
    int lane = threadIdx.x & 63;
    int val = (i < n) ? deg[i] : 0;
    int scan = val;
    #pragma unroll
    for (int off = 1; off < 64; off <<= 1) {
        int t = __shfl_up(scan, off);
        if (lane >= off) scan += t;
    }
    int excl = scan - val;
    int total = __shfl(scan, 63);
    int wb = 0;
    if (lane == 0) wb = atomicAdd(counter, total);
    wb = __shfl(wb, 0);
    if (i < n) { base[i] = wb + excl; cursor[i] = wb + excl; }
}

__global__ void k_scatter(const int* __restrict__ eint, int E,
                          const float* __restrict__ dinv, int n,
                          int* __restrict__ cursor, int2* __restrict__ ew) {
    int e = blockIdx.x * blockDim.x + threadIdx.x;
    if (e >= E) return;
    int r = eint[e];
    int c = eint[E + e];
    if ((unsigned)r >= (unsigned)n || (unsigned)c >= (unsigned)n) return;
    int p = atomicAdd(&cursor[c], 1);
    int2 v; v.x = r; v.y = __float_as_int(dinv[r] * dinv[c]);
    ew[p] = v;
}

// ---------------------------------------------------------------------------
// Weight prep: W (nstack, K, N) fp32 -> Wt (nstack*N rows, K) bf16 (transposed).
// ---------------------------------------------------------------------------
__global__ void k_wprep(const float* __restrict__ W, unsigned short* __restrict__ Wt,
                        int K, int N) {
    int j = blockIdx.y;
    int idx = blockIdx.x * 256 + threadIdx.x;
    if (idx >= K * N) return;
    int k = idx / N, nn = idx - k * N;
    Wt[(size_t)j * N * K + (size_t)nn * K + k] = f2bf(W[(size_t)j * K * N + idx]);
}

__global__ void k_cast4(const float* __restrict__ x, unsigned short* __restrict__ y, int n4) {
    int i = blockIdx.x * 256 + threadIdx.x;
    if (i >= n4) return;
    float4 v = ((const float4*)x)[i];
    ushort4 o;
    o.x = f2bf(v.x); o.y = f2bf(v.y); o.z = f2bf(v.z); o.w = f2bf(v.w);
    ((ushort4*)y)[i] = o;
}

// ---------------------------------------------------------------------------
// m97-clone MFMA GEMM (the one guide-proven recipe not yet tried here):
// 128 x TILEN tile, BK=32, 256 thr / 4 waves (2 row-halves x 2 col-halves),
// TM=4 x TN=TILEN/32 acc, staging via __builtin_amdgcn_global_load_lds
// width=16 (async DMA, deep HW queue — no VGPR round trip, no vmcnt(0)
// on a shallow queue), UNPADDED lane-ordered LDS (m97 ran this way),
// ds_read_b128 fragments, 2-barrier K-loop.
//   C_j (M x TILEN) = concat(A0,A1,A2)(M x K, piece width W) @ Bt_j^T + bias_j
// grid = (ceil(M/128), npieces); j = blockIdx.y.
// ---------------------------------------------------------------------------
template<int TILEN, bool BFOUT>
__global__ __launch_bounds__(256) void k_gemm(
    const unsigned short* __restrict__ A0, const unsigned short* __restrict__ A1,
    const unsigned short* __restrict__ A2, int W, int M, int K,
    const unsigned short* __restrict__ Bt,   // (npieces*TILEN) rows x K
    const float* __restrict__ bias,          // npieces*TILEN
    unsigned short* __restrict__ C0, unsigned short* __restrict__ C1,
    unsigned short* __restrict__ C2, float* __restrict__ Cf)
{
    constexpr int TM = 4;
    constexpr int TN = TILEN / 32;           // 4 or 2
    __shared__ __align__(16) unsigned short As[128 * 32];
    __shared__ __align__(16) unsigned short Bs[TILEN * 32];

    int t = threadIdx.x;
    int wave = t >> 6, lane = t & 63;
    int m16 = lane & 15, q = lane >> 4;
    int j = blockIdx.y;
    int row0 = blockIdx.x * 128;
    int wr = (wave & 1) * 64;
    int wc = (wave >> 1) * (TILEN / 2);

    // staging geometry: one wave-inst = 64 lanes x 16 B = 16 rows x 64 B
    int lr = lane >> 2, lch = lane & 3;
    int ra0 = (wave * 2 + 0) * 16 + lr;      // rows 0..127 across 8 wave-insts
    int ra1 = (wave * 2 + 1) * 16 + lr;
    int ga0 = row0 + ra0; if (ga0 >= M) ga0 = M - 1;   // clamp; stores guarded
    int ga1 = row0 + ra1; if (ga1 >= M) ga1 = M - 1;
    size_t boff0 = (size_t)(j * TILEN + ra0) * K;
    size_t boff1 = (size_t)(j * TILEN + ra1) * K;
    size_t boffS = (size_t)(j * TILEN + wave * 16 + lr) * K;   // TILEN=64 path

    f4 acc[TM][TN];
    #pragma unroll
    for (int i = 0; i < TM; i++)
        #pragma unroll
        for (int jj = 0; jj < TN; jj++) acc[i][jj] = (f4){0.f, 0.f, 0.f, 0.f};

    for (int kk = 0; kk < K; kk += 32) {
        int pi = kk / W;
        const unsigned short* Ap = (pi == 0) ? A0 : ((pi == 1) ? A1 : A2);
        int kl = kk - pi * W;                // piece-local k: A only (B uses kk)

        __syncthreads();                     // prev-iter ds_reads complete
        gload16(&Ap[(size_t)ga0 * W + kl + lch * 8], &As[(wave * 2 + 0) * 512]);
        gload16(&Ap[(size_t)ga1 * W + kl + lch * 8], &As[(wave * 2 + 1) * 512]);
        if (TILEN == 128) {
            gload16(&Bt[boff0 + kk + lch * 8], &Bs[(wave * 2 + 0) * 512]);
            gload16(&Bt[boff1 + kk + lch * 8], &Bs[(wave * 2 + 1) * 512]);
        } else {
            gload16(&Bt[boffS + kk + lch * 8], &Bs[wave * 512]);
        }
        __syncthreads();                     // drains vmcnt(0): DMA complete

        bf8 af[TM], bfr[TN];
        #pragma unroll
        for (int tm = 0; tm < TM; tm++)
            af[tm] = *(const bf8*)&As[(wr + tm * 16 + m16) * 32 + q * 8];
        #pragma unroll
        for (int tn = 0; tn < TN; tn++)
            bfr[tn] = *(const bf8*)&Bs[(wc + tn * 16 + m16) * 32 + q * 8];
        #pragma unroll
        for (int tm = 0; tm < TM; tm++)
            #pragma unroll
            for (int tn = 0; tn < TN; tn++)
                acc[tm][tn] = __builtin_amdgcn_mfma_f32_16x16x32_bf16(
                    af[tm], bfr[tn], acc[tm][tn], 0, 0, 0);
    }

    unsigned short* Cj = (j == 0) ? C0 : ((j == 1) ? C1 : C2);
    #pragma unroll
    for (int tn = 0; tn < TN; tn++) {
        int col = wc + tn * 16 + m16;
        float bi = bias[j * TILEN + col];
        #pragma unroll
        for (int tm = 0; tm < TM; tm++) {
            #pragma unroll
            for (int r = 0; r < 4; r++) {
                int row = row0 + wr + tm * 16 + q * 4 + r;
                if (row >= M) continue;
                float v = acc[tm][tn][r] + bi;
                if (BFOUT) Cj[(size_t)row * TILEN + col] = f2bf(v);
                else       Cf[(size_t)row * TILEN + col] = v;
            }
        }
    }
}

// ---------------------------------------------------------------------------
// SpMM (bf16 in/out, fp32 accumulate), packed edges, unroll-8.
// ---------------------------------------------------------------------------
template<int V, bool DUAL>
__global__ __launch_bounds__(256) void k_spmm(
    const unsigned short* __restrict__ S1, const unsigned short* __restrict__ S2,
    unsigned short* __restrict__ D1, unsigned short* __restrict__ D2, int width,
    const int* __restrict__ base, const int* __restrict__ deg,
    const int2* __restrict__ ew, int n)
{
    int node = blockIdx.x * 4 + threadIdx.y;
    if (node >= n) return;
    int tx = threadIdx.x;
    float a1[V], a2[V];
    #pragma unroll
    for (int v = 0; v < V; v++) { a1[v] = 0.f; if (DUAL) a2[v] = 0.f; }
    int b = base[node], end = b + deg[node];
    const unsigned short* P1 = S1 + tx * V;
    const unsigned short* P2 = DUAL ? (S2 + tx * V) : nullptr;
    constexpr int UN = 8;
    int e = b;
    for (; e + UN <= end; e += UN) {
        int2 ev[UN];
        #pragma unroll
        for (int u = 0; u < UN; u++) ev[u] = ew[e + u];
        unsigned int g1[UN], g2[UN];
        #pragma unroll
        for (int u = 0; u < UN; u++) {
            if (V == 2) g1[u] = *(const unsigned int*)(P1 + (size_t)ev[u].x * width);
            else        g1[u] = P1[(size_t)ev[u].x * width];
            if (DUAL) {
                if (V == 2) g2[u] = *(const unsigned int*)(P2 + (size_t)ev[u].x * width);
                else        g2[u] = P2[(size_t)ev[u].x * width];
            }
        }
        #pragma unroll
        for (int u = 0; u < UN; u++) {
            float we = __int_as_float(ev[u].y);
            if (V == 2) {
                a1[0] += we * bf2f((unsigned short)(g1[u] & 0xffff));
                a1[1] += we * bf2f((unsigned short)(g1[u] >> 16));
                if (DUAL) {
                    a2[0] += we * bf2f((unsigned short)(g2[u] & 0xffff));
                    a2[1] += we * bf2f((unsigned short)(g2[u] >> 16));
                }
            } else {
                a1[0] += we * bf2f((unsigned short)g1[u]);
                if (DUAL) a2[0] += we * bf2f((unsigned short)g2[u]);
            }
        }
    }
    for (; e < end; ++e) {
        int2 ev = ew[e];
        float we = __int_as_float(ev.y);
        if (V == 2) {
            unsigned int u1 = *(const unsigned int*)(P1 + (size_t)ev.x * width);
            a1[0] += we * bf2f((unsigned short)(u1 & 0xffff));
            a1[1] += we * bf2f((unsigned short)(u1 >> 16));
            if (DUAL) {
                unsigned int u2 = *(const unsigned int*)(P2 + (size_t)ev.x * width);
                a2[0] += we * bf2f((unsigned short)(u2 & 0xffff));
                a2[1] += we * bf2f((unsigned short)(u2 >> 16));
            }
        } else {
            a1[0] += we * bf2f(P1[(size_t)ev.x * width]);
            if (DUAL) a2[0] += we * bf2f(P2[(size_t)ev.x * width]);
        }
    }
    size_t o = (size_t)node * width + tx * V;
    if (V == 2) {
        ushort2 o1; o1.x = f2bf(a1[0]); o1.y = f2bf(a1[1]);
        *(ushort2*)&D1[o] = o1;
        if (DUAL) { ushort2 o2; o2.x = f2bf(a2[0]); o2.y = f2bf(a2[1]);
                    *(ushort2*)&D2[o] = o2; }
    } else {
        D1[o] = f2bf(a1[0]);
        if (DUAL) D2[o] = f2bf(a2[0]);
    }
}

// ---------------------------------------------------------------------------
// BatchNorm: stats + finalize + in-place apply (bf16, battle-tested r5).
// ---------------------------------------------------------------------------
__global__ void k_bnstats(const unsigned short* __restrict__ p0,
                          const unsigned short* __restrict__ p1,
                          const unsigned short* __restrict__ p2,
                          float* __restrict__ sums, float* __restrict__ sumsq, int n)
{
    int c = threadIdx.x;
    int cc = c & 127;
    int pi = c >> 7;
    const unsigned short* src = (pi == 0) ? p0 : ((pi == 1) ? p1 : p2);
    float s = 0.f, s2 = 0.f;
    for (int r = blockIdx.x; r < n; r += gridDim.x) {
        float v = bf2f(src[(size_t)r * 128 + cc]);
        s += v; s2 += v * v;
    }
    atomicAdd(&sums[c], s);
    atomicAdd(&sumsq[c], s2);
}

__global__ void k_bnfin(const float* __restrict__ sums, const float* __restrict__ sumsq,
                        const float* __restrict__ g, const float* __restrict__ bb,
                        float* __restrict__ scale, float* __restrict__ shift,
                        int cat, float invn)
{
    int c = threadIdx.x;
    if (c >= cat) return;
    float mu  = sums[c] * invn;
    float var = sumsq[c] * invn - mu * mu;
    float sc  = g[c] * rsqrtf(var + 1e-5f);
    scale[c] = sc;
    shift[c] = bb[c] - mu * sc;
}

__global__ void k_bnapply(unsigned short* __restrict__ p0, unsigned short* __restrict__ p1,
                          unsigned short* __restrict__ p2,
                          const float* __restrict__ scale, const float* __restrict__ shift,
                          int n)
{
    int c = threadIdx.x;              // 384
    int cc = c & 127;
    int pi = c >> 7;
    unsigned short* src = (pi == 0) ? p0 : ((pi == 1) ? p1 : p2);
    float sc = scale[c], sh = shift[c];
    for (int r = blockIdx.x; r < n; r += gridDim.x) {
        size_t idx = (size_t)r * 128 + cc;
        float v = bf2f(src[idx]) * sc + sh;
        src[idx] = f2bf(fmaxf(v, 0.0f));
    }
}

// Diagnostic: if workspace is too small, surface ws_size (MB) via d_out.
__global__ void k_diag(float* out, float val, int n) {
    int i = blockIdx.x * blockDim.x + threadIdx.x;
    if (i < n) out[i] = val;
}

// ---------------------------------------------------------------------------
extern "C" void kernel_launch(void* const* d_in, const int* in_sizes, int n_in,
                              void* d_out, int out_size, void* d_ws, size_t ws_size,
                              hipStream_t stream)
{
    const float* x    = (const float*)d_in[0];
    const void*  ei   = d_in[1];
    const float* W0   = (const float*)d_in[2];
    const float* b0   = (const float*)d_in[3];
    const float* W1   = (const float*)d_in[4];
    const float* b1   = (const float*)d_in[5];
    const float* W2   = (const float*)d_in[6];
    const float* b2   = (const float*)d_in[7];
    const float* bn0g = (const float*)d_in[8];
    const float* bn0b = (const float*)d_in[9];
    const float* bn1g = (const float*)d_in[10];
    const float* bn1b = (const float*)d_in[11];
    const float* fpW  = (const float*)d_in[12];
    const float* fpb  = (const float*)d_in[13];
    float* out = (float*)d_out;

    const int N    = in_sizes[0] / IN_C;
    const int twoE = in_sizes[1];
    const int E    = twoE / 2;

    // ---- workspace carve (~184 MB; budget 256 MiB) ----
    char* p = (char*)d_ws;
    auto alloc = [&](size_t bytes) -> char* {
        char* r = p; p += (bytes + 255) & ~(size_t)255; return r;
    };
    unsigned short* U[6];
    for (int i = 0; i < 6; i++) U[i] = (unsigned short*)alloc((size_t)N * 128 * 2);
    unsigned short* Wt0 = (unsigned short*)alloc((size_t)3 * 128 * 128 * 2);
    unsigned short* Wt1 = (unsigned short*)alloc((size_t)3 * 384 * 128 * 2);
    unsigned short* Wt2 = (unsigned short*)alloc((size_t)3 * 384 * 64 * 2);
    unsigned short* WtF = (unsigned short*)alloc((size_t)192 * 64 * 2);
    float* dinv  = (float*)alloc((size_t)N * 4);
    int2*  ew    = (int2*)alloc((size_t)E * 8);
    float* sums  = (float*)alloc(2 * 384 * 4);
    float* sumsq = sums + 384;
    float* scale = (float*)alloc(384 * 4);
    float* shift = (float*)alloc(384 * 4);
    int* deg     = (int*)alloc((size_t)N * 4);
    int* base    = (int*)alloc((size_t)N * 4);
    int* cursor  = (int*)alloc((size_t)N * 4);
    int* eint    = (int*)alloc((size_t)twoE * 4);
    int* counter = (int*)alloc(4);
    int* flag    = (int*)alloc(4);

    size_t required = (size_t)(p - (char*)d_ws);
    if (required > ws_size) {
        k_diag<<<(out_size + 255) / 256, 256, 0, stream>>>(
            out, (float)(ws_size >> 20), out_size);
        return;
    }

    const int T = 256;
    dim3 spmm_blk(64, 4);
    int  spmm_grid = (N + 3) / 4;
    int  gx = (N + 127) / 128;

    // ---- weight prep + input cast ----
    k_wprep<<<dim3((128 * 128 + 255) / 256, 3), T, 0, stream>>>(W0, Wt0, 128, 128);
    k_wprep<<<dim3((384 * 128 + 255) / 256, 3), T, 0, stream>>>(W1, Wt1, 384, 128);
    k_wprep<<<dim3((384 * 64  + 255) / 256, 3), T, 0, stream>>>(W2, Wt2, 384, 64);
    k_wprep<<<dim3((192 * 64  + 255) / 256, 1), T, 0, stream>>>(fpW, WtF, 192, 64);
    unsigned short* Xb = U[3];
    k_cast4<<<((N * 128 / 4) + 255) / 256, T, 0, stream>>>(x, Xb, N * 128 / 4);

    // ---- graph build ----
    hipMemsetAsync(deg, 0, (size_t)N * 4, stream);
    hipMemsetAsync(counter, 0, 4, stream);
    k_detect<<<1, 64, 0, stream>>>((const long long*)ei, N, flag);
    k_cvt_hist<<<(twoE + T - 1) / T, T, 0, stream>>>(ei, twoE, E, flag, eint, deg, N);
    k_dinv<<<(N + T - 1) / T, T, 0, stream>>>(deg, dinv, N);
    k_alloc<<<(N + T - 1) / T, T, 0, stream>>>(deg, base, cursor, counter, N);
    k_scatter<<<(E + T - 1) / T, T, 0, stream>>>(eint, E, dinv, N, cursor, ew);

    // ---- layer 0: Xb(=U3) -> G0:U0, G1:U1, G2:U2 ----
    k_gemm<128, true><<<dim3(gx, 3), T, 0, stream>>>(Xb, Xb, Xb, 128, N, 128,
        Wt0, b0, U[0], U[1], U[2], nullptr);
    // H1 = A*G1 -> U4 ; T = A*G2 -> U5 ; H2 = A*T -> U3
    k_spmm<2, true ><<<spmm_grid, spmm_blk, 0, stream>>>(U[1], U[2], U[4], U[5], 128,
                                                         base, deg, ew, N);
    k_spmm<2, false><<<spmm_grid, spmm_blk, 0, stream>>>(U[5], nullptr, U[3], nullptr, 128,
                                                         base, deg, ew, N);
    hipMemsetAsync(sums, 0, 2 * 384 * 4, stream);
    k_bnstats<<<2048, 384, 0, stream>>>(U[0], U[4], U[3], sums, sumsq, N);
    k_bnfin<<<1, 384, 0, stream>>>(sums, sumsq, bn0g, bn0b, scale, shift, 384, 1.0f / N);
    k_bnapply<<<2048, 384, 0, stream>>>(U[0], U[4], U[3], scale, shift, N);
    // layer-0 output (post BN+ReLU, in place): (U0, U4, U3)

    // ---- layer 1: (U0,U4,U3) -> G0:U1, G1:U2, G2:U5 ----
    k_gemm<128, true><<<dim3(gx, 3), T, 0, stream>>>(U[0], U[4], U[3], 128, N, 384,
        Wt1, b1, U[1], U[2], U[5], nullptr);
    // H1 = A*G1 -> U0 ; T = A*G2 -> U4 ; H2 = A*T -> U3
    k_spmm<2, true ><<<spmm_grid, spmm_blk, 0, stream>>>(U[2], U[5], U[0], U[4], 128,
                                                         base, deg, ew, N);
    k_spmm<2, false><<<spmm_grid, spmm_blk, 0, stream>>>(U[4], nullptr, U[3], nullptr, 128,
                                                         base, deg, ew, N);
    hipMemsetAsync(sums, 0, 2 * 384 * 4, stream);
    k_bnstats<<<2048, 384, 0, stream>>>(U[1], U[0], U[3], sums, sumsq, N);
    k_bnfin<<<1, 384, 0, stream>>>(sums, sumsq, bn1g, bn1b, scale, shift, 384, 1.0f / N);
    k_bnapply<<<2048, 384, 0, stream>>>(U[1], U[0], U[3], scale, shift, N);
    // layer-1 output: (U1, U0, U3)

    // ---- layer 2: (U1,U0,U3) -> 64-wide pieces in halves of U2/U4/U5 ----
    unsigned short* V2a = U[2];
    unsigned short* V2b = U[2] + (size_t)N * 64;
    unsigned short* V4a = U[4];
    unsigned short* V4b = U[4] + (size_t)N * 64;
    unsigned short* V5a = U[5];
    unsigned short* V5b = U[5] + (size_t)N * 64;
    k_gemm<64, true><<<dim3(gx, 3), T, 0, stream>>>(U[1], U[0], U[3], 128, N, 384,
        Wt2, b2, V2a, V2b, V4a, nullptr);
    // A*L1(V2b) -> V4b ; T = A*L2(V4a) -> V5a ; A*T -> V5b
    k_spmm<1, true ><<<spmm_grid, spmm_blk, 0, stream>>>(V2b, V4a, V4b, V5a, 64,
                                                         base, deg, ew, N);
    k_spmm<1, false><<<spmm_grid, spmm_blk, 0, stream>>>(V5a, nullptr, V5b, nullptr, 64,
                                                         base, deg, ew, N);

    // ---- final projection: out = concat(V2a, V4b, V5b)(N x 192) @ fpW + fpb ----
    k_gemm<64, false><<<dim3(gx, 1), T, 0, stream>>>(V2a, V4b, V5b, 64, N, 192,
        WtF, fpb, nullptr, nullptr, nullptr, out);
}

// Round 13
// 1235.185 us; speedup vs baseline: 1.2183x; 1.0640x over previous
//
#include <hip/hip_runtime.h>
#include <cstdint>
#include <cstddef>

#define IN_C 128
#define HIDc 128
#define OUTc 64

using bf8 = __attribute__((ext_vector_type(8))) __bf16;
using f4  = __attribute__((ext_vector_type(4))) float;

// ---- bf16 helpers (RNE) ----
__device__ __forceinline__ unsigned short f2bf(float f) {
    unsigned int u = __float_as_uint(f);
    unsigned int r = (u + 0x7FFFu + ((u >> 16) & 1u)) >> 16;
    return (unsigned short)r;
}
__device__ __forceinline__ float bf2f(unsigned short h) {
    return __uint_as_float(((unsigned int)h) << 16);
}

// Async global->LDS, 16 B per lane (guide §5, m97/m104): LDS dest is the
// wave-uniform base; HW places lane i's 16 B at base + i*16.
__device__ __forceinline__ void gload16(const unsigned short* g, unsigned short* l) {
    __builtin_amdgcn_global_load_lds(
        (const __attribute__((address_space(1))) unsigned int*)g,
        (__attribute__((address_space(3))) unsigned int*)l, 16, 0, 0);
}

// ---------------------------------------------------------------------------
// Graph build (battle-tested r3-r12).
// ---------------------------------------------------------------------------
__global__ void k_detect(const long long* ei, int n_nodes, int* flag) {
    int t = threadIdx.x;                    // blockDim = 64
    long long v = ei[t];
    int ok = (v >= 0 && v < (long long)n_nodes) ? 1 : 0;
    unsigned long long m = __ballot(ok);
    if (t == 0) *flag = (m == ~0ull) ? 1 : 0;
}

__global__ void k_cvt_hist(const void* ei, int twoE, int E, const int* flag,
                           int* __restrict__ out, int* __restrict__ deg, int n) {
    int i = blockIdx.x * blockDim.x + threadIdx.x;
    if (i >= twoE) return;
    int v = (*flag) ? (int)((const long long*)ei)[i] : ((const int*)ei)[i];
    out[i] = v;
    if (i >= E && (unsigned)v < (unsigned)n) atomicAdd(&deg[v], 1);
}

__global__ void k_dinv(const int* __restrict__ deg, float* __restrict__ dinv, int n) {
    int i = blockIdx.x * blockDim.x + threadIdx.x;
    if (i < n) dinv[i] = (deg[i] > 0) ? rsqrtf((float)deg[i]) : 0.0f;
}

__global__ void k_alloc(const int* __restrict__ deg, int* __restrict__ base,
                        int* __restrict__ cursor, int* __restrict__ counter, int n) {
    int i = blockIdx.x * blockDim.x + threadIdx.x;
    int lane = threadIdx.x & 63;
    int val = (i < n) ? deg[i] : 0;
    int scan = val;
    #pragma unroll
    for (int off = 1; off < 64; off <<= 1) {
        int t = __shfl_up(scan, off);
        if (lane >= off) scan += t;
    }
    int excl = scan - val;
    int total = __shfl(scan, 63);
    int wb = 0;
    if (lane == 0) wb = atomicAdd(counter, total);
    wb = __shfl(wb, 0);
    if (i < n) { base[i] = wb + excl; cursor[i] = wb + excl; }
}

__global__ void k_scatter(const int* __restrict__ eint, int E,
                          const float* __restrict__ dinv, int n,
                          int* __restrict__ cursor, int2* __restrict__ ew) {
    int e = blockIdx.x * blockDim.x + threadIdx.x;
    if (e >= E) return;
    int r = eint[e];
    int c = eint[E + e];
    if ((unsigned)r >= (unsigned)n || (unsigned)c >= (unsigned)n) return;
    int p = atomicAdd(&cursor[c], 1);
    int2 v; v.x = r; v.y = __float_as_int(dinv[r] * dinv[c]);
    ew[p] = v;
}

// ---------------------------------------------------------------------------
// Weight prep: W (nstack, K, N) fp32 -> Wt (nstack*N rows, K) bf16 (transposed).
// ---------------------------------------------------------------------------
__global__ void k_wprep(const float* __restrict__ W, unsigned short* __restrict__ Wt,
                        int K, int N) {
    int j = blockIdx.y;
    int idx = blockIdx.x * 256 + threadIdx.x;
    if (idx >= K * N) return;
    int k = idx / N, nn = idx - k * N;
    Wt[(size_t)j * N * K + (size_t)nn * K + k] = f2bf(W[(size_t)j * K * N + idx]);
}

__global__ void k_cast4(const float* __restrict__ x, unsigned short* __restrict__ y, int n4) {
    int i = blockIdx.x * 256 + threadIdx.x;
    if (i >= n4) return;
    float4 v = ((const float4*)x)[i];
    ushort4 o;
    o.x = f2bf(v.x); o.y = f2bf(v.y); o.z = f2bf(v.z); o.w = f2bf(v.w);
    ((ushort4*)y)[i] = o;
}

// ---------------------------------------------------------------------------
// m97-clone MFMA GEMM (r12 K-loop VERBATIM — it broke the 6%-MfmaUtil wall)
// + r13 epilogue: acc staged through LDS, streamed out as full 128-B lines
// (r11 measured 3.3x write amp from 32-B lane-group stores). Per-piece ldc
// lets outputs land in interleaved pair buffers for the dual spmm.
//   C_j (M x TILEN) = concat(A0,A1,A2)(M x K, piece width W) @ Bt_j^T + bias_j
// grid = (ceil(M/128), npieces); j = blockIdx.y.
// ---------------------------------------------------------------------------
template<int TILEN, bool BFOUT>
__global__ __launch_bounds__(256) void k_gemm(
    const unsigned short* __restrict__ A0, const unsigned short* __restrict__ A1,
    const unsigned short* __restrict__ A2, int W, int M, int K,
    const unsigned short* __restrict__ Bt,   // (npieces*TILEN) rows x K
    const float* __restrict__ bias,          // npieces*TILEN
    unsigned short* __restrict__ C0, int ldc0,
    unsigned short* __restrict__ C1, int ldc1,
    unsigned short* __restrict__ C2, int ldc2,
    float* __restrict__ Cf, int ldcf)
{
    constexpr int TM = 4;
    constexpr int TN = TILEN / 32;           // 4 or 2
    __shared__ __align__(16) unsigned short As[128 * 32];
    __shared__ __align__(16) unsigned short Bs[TILEN * 32];
    __shared__ __align__(16) unsigned char  Cs[16384];

    int t = threadIdx.x;
    int wave = t >> 6, lane = t & 63;
    int m16 = lane & 15, q = lane >> 4;
    int j = blockIdx.y;
    int row0 = blockIdx.x * 128;
    int wr = (wave & 1) * 64;
    int wc = (wave >> 1) * (TILEN / 2);

    // staging geometry: one wave-inst = 64 lanes x 16 B = 16 rows x 64 B
    int lr = lane >> 2, lch = lane & 3;
    int ra0 = (wave * 2 + 0) * 16 + lr;
    int ra1 = (wave * 2 + 1) * 16 + lr;
    int ga0 = row0 + ra0; if (ga0 >= M) ga0 = M - 1;
    int ga1 = row0 + ra1; if (ga1 >= M) ga1 = M - 1;
    size_t boff0 = (size_t)(j * TILEN + ra0) * K;
    size_t boff1 = (size_t)(j * TILEN + ra1) * K;
    size_t boffS = (size_t)(j * TILEN + wave * 16 + lr) * K;

    f4 acc[TM][TN];
    #pragma unroll
    for (int i = 0; i < TM; i++)
        #pragma unroll
        for (int jj = 0; jj < TN; jj++) acc[i][jj] = (f4){0.f, 0.f, 0.f, 0.f};

    for (int kk = 0; kk < K; kk += 32) {
        int pi = kk / W;
        const unsigned short* Ap = (pi == 0) ? A0 : ((pi == 1) ? A1 : A2);
        int kl = kk - pi * W;

        __syncthreads();
        gload16(&Ap[(size_t)ga0 * W + kl + lch * 8], &As[(wave * 2 + 0) * 512]);
        gload16(&Ap[(size_t)ga1 * W + kl + lch * 8], &As[(wave * 2 + 1) * 512]);
        if (TILEN == 128) {
            gload16(&Bt[boff0 + kk + lch * 8], &Bs[(wave * 2 + 0) * 512]);
            gload16(&Bt[boff1 + kk + lch * 8], &Bs[(wave * 2 + 1) * 512]);
        } else {
            gload16(&Bt[boffS + kk + lch * 8], &Bs[wave * 512]);
        }
        __syncthreads();

        bf8 af[TM], bfr[TN];
        #pragma unroll
        for (int tm = 0; tm < TM; tm++)
            af[tm] = *(const bf8*)&As[(wr + tm * 16 + m16) * 32 + q * 8];
        #pragma unroll
        for (int tn = 0; tn < TN; tn++)
            bfr[tn] = *(const bf8*)&Bs[(wc + tn * 16 + m16) * 32 + q * 8];
        #pragma unroll
        for (int tm = 0; tm < TM; tm++)
            #pragma unroll
            for (int tn = 0; tn < TN; tn++)
                acc[tm][tn] = __builtin_amdgcn_mfma_f32_16x16x32_bf16(
                    af[tm], bfr[tn], acc[tm][tn], 0, 0, 0);
    }

    // ---- epilogue: LDS-staged, full-line coalesced stores ----
    constexpr int EB  = BFOUT ? 2 : 4;
    constexpr int RB  = TILEN * EB;          // bytes per C row (<=256)
    constexpr int CPR = RB / 16;             // uint4 chunks per row
    constexpr int PT  = 64 * CPR / 256;      // chunks per thread per half
    char* Cb;
    long  ldb;
    if (BFOUT) {
        unsigned short* Cj = (j == 0) ? C0 : ((j == 1) ? C1 : C2);
        int lj = (j == 0) ? ldc0 : ((j == 1) ? ldc1 : ldc2);
        Cb = (char*)Cj; ldb = (long)lj * 2;
    } else {
        Cb = (char*)Cf; ldb = (long)ldcf * 4;
    }
    #pragma unroll
    for (int half = 0; half < 2; half++) {
        __syncthreads();
        if ((wave & 1) == half) {
            #pragma unroll
            for (int tn = 0; tn < TN; tn++) {
                int col = wc + tn * 16 + m16;
                float bi = bias[j * TILEN + col];
                #pragma unroll
                for (int tm = 0; tm < TM; tm++) {
                    #pragma unroll
                    for (int r = 0; r < 4; r++) {
                        int lrow = tm * 16 + q * 4 + r;
                        float v = acc[tm][tn][r] + bi;
                        if (BFOUT) ((unsigned short*)Cs)[lrow * TILEN + col] = f2bf(v);
                        else       ((float*)Cs)[lrow * TILEN + col] = v;
                    }
                }
            }
        }
        __syncthreads();
        #pragma unroll
        for (int i = 0; i < PT; i++) {
            int idx  = i * 256 + t;
            int lrow = idx / CPR;
            int c16  = idx - lrow * CPR;
            int grow = row0 + half * 64 + lrow;
            if (grow < M)
                *(uint4*)(Cb + (size_t)grow * ldb + c16 * 16) = ((const uint4*)Cs)[idx];
        }
    }
}

// ---------------------------------------------------------------------------
// Dual-source SpMM over an INTERLEAVED pair buffer: S row = [p1row | p2row],
// 2*PW bf16 per node -> ONE 8B(4B)/lane gather per edge fetches both pieces
// (512 B/wave for PW=128). Half-wave 0 -> D1 (piece1), half-wave 1 -> D2.
// fp32 accumulate, unroll-8, packed edges. One wave per node.
// ---------------------------------------------------------------------------
template<int PW>
__global__ __launch_bounds__(256) void k_spmm2i(
    const unsigned short* __restrict__ S,
    unsigned short* __restrict__ D1, unsigned short* __restrict__ D2,
    const int* __restrict__ base, const int* __restrict__ deg,
    const int2* __restrict__ ew, int n)
{
    int node = blockIdx.x * 4 + threadIdx.y;
    if (node >= n) return;
    int lane = threadIdx.x;
    constexpr int CV = PW / 32;              // cols per lane: 4 or 2
    int half = lane >> 5, lx = lane & 31;
    const unsigned short* Sp = S + half * PW + lx * CV;
    float acc[CV];
    #pragma unroll
    for (int v = 0; v < CV; v++) acc[v] = 0.f;
    int b = base[node], end = b + deg[node];
    constexpr int UN = 8;
    int e = b;
    for (; e + UN <= end; e += UN) {
        int2 ev[UN];
        #pragma unroll
        for (int u = 0; u < UN; u++) ev[u] = ew[e + u];
        ushort4 g4[UN]; ushort2 g2[UN];
        #pragma unroll
        for (int u = 0; u < UN; u++) {
            if (CV == 4) g4[u] = *(const ushort4*)(Sp + (size_t)ev[u].x * (2 * PW));
            else         g2[u] = *(const ushort2*)(Sp + (size_t)ev[u].x * (2 * PW));
        }
        #pragma unroll
        for (int u = 0; u < UN; u++) {
            float we = __int_as_float(ev[u].y);
            if (CV == 4) {
                acc[0] += we * bf2f(g4[u].x); acc[1] += we * bf2f(g4[u].y);
                acc[2] += we * bf2f(g4[u].z); acc[3] += we * bf2f(g4[u].w);
            } else {
                acc[0] += we * bf2f(g2[u].x); acc[1] += we * bf2f(g2[u].y);
            }
        }
    }
    for (; e < end; ++e) {
        int2 ev = ew[e];
        float we = __int_as_float(ev.y);
        if (CV == 4) {
            ushort4 g = *(const ushort4*)(Sp + (size_t)ev.x * (2 * PW));
            acc[0] += we * bf2f(g.x); acc[1] += we * bf2f(g.y);
            acc[2] += we * bf2f(g.z); acc[3] += we * bf2f(g.w);
        } else {
            ushort2 g = *(const ushort2*)(Sp + (size_t)ev.x * (2 * PW));
            acc[0] += we * bf2f(g.x); acc[1] += we * bf2f(g.y);
        }
    }
    unsigned short* D = half ? D2 : D1;
    size_t o = (size_t)node * PW + lx * CV;
    if (CV == 4) {
        ushort4 ov;
        ov.x = f2bf(acc[0]); ov.y = f2bf(acc[1]);
        ov.z = f2bf(acc[2]); ov.w = f2bf(acc[3]);
        *(ushort4*)&D[o] = ov;
    } else {
        ushort2 ov; ov.x = f2bf(acc[0]); ov.y = f2bf(acc[1]);
        *(ushort2*)&D[o] = ov;
    }
}

// ---------------------------------------------------------------------------
// Single-source SpMM (plain layout), unroll-8 (battle-tested r12).
// ---------------------------------------------------------------------------
template<int V>
__global__ __launch_bounds__(256) void k_spmm(
    const unsigned short* __restrict__ S1, unsigned short* __restrict__ D1, int width,
    const int* __restrict__ base, const int* __restrict__ deg,
    const int2* __restrict__ ew, int n)
{
    int node = blockIdx.x * 4 + threadIdx.y;
    if (node >= n) return;
    int tx = threadIdx.x;
    float a1[V];
    #pragma unroll
    for (int v = 0; v < V; v++) a1[v] = 0.f;
    int b = base[node], end = b + deg[node];
    const unsigned short* P1 = S1 + tx * V;
    constexpr int UN = 8;
    int e = b;
    for (; e + UN <= end; e += UN) {
        int2 ev[UN];
        #pragma unroll
        for (int u = 0; u < UN; u++) ev[u] = ew[e + u];
        unsigned int g1[UN];
        #pragma unroll
        for (int u = 0; u < UN; u++) {
            if (V == 2) g1[u] = *(const unsigned int*)(P1 + (size_t)ev[u].x * width);
            else        g1[u] = P1[(size_t)ev[u].x * width];
        }
        #pragma unroll
        for (int u = 0; u < UN; u++) {
            float we = __int_as_float(ev[u].y);
            if (V == 2) {
                a1[0] += we * bf2f((unsigned short)(g1[u] & 0xffff));
                a1[1] += we * bf2f((unsigned short)(g1[u] >> 16));
            } else {
                a1[0] += we * bf2f((unsigned short)g1[u]);
            }
        }
    }
    for (; e < end; ++e) {
        int2 ev = ew[e];
        float we = __int_as_float(ev.y);
        if (V == 2) {
            unsigned int u1 = *(const unsigned int*)(P1 + (size_t)ev.x * width);
            a1[0] += we * bf2f((unsigned short)(u1 & 0xffff));
            a1[1] += we * bf2f((unsigned short)(u1 >> 16));
        } else {
            a1[0] += we * bf2f(P1[(size_t)ev.x * width]);
        }
    }
    size_t o = (size_t)node * width + tx * V;
    if (V == 2) {
        ushort2 o1; o1.x = f2bf(a1[0]); o1.y = f2bf(a1[1]);
        *(ushort2*)&D1[o] = o1;
    } else {
        D1[o] = f2bf(a1[0]);
    }
}

// ---------------------------------------------------------------------------
// BatchNorm: stats + finalize + in-place apply (bf16, battle-tested r5).
// ---------------------------------------------------------------------------
__global__ void k_bnstats(const unsigned short* __restrict__ p0,
                          const unsigned short* __restrict__ p1,
                          const unsigned short* __restrict__ p2,
                          float* __restrict__ sums, float* __restrict__ sumsq, int n)
{
    int c = threadIdx.x;
    int cc = c & 127;
    int pi = c >> 7;
    const unsigned short* src = (pi == 0) ? p0 : ((pi == 1) ? p1 : p2);
    float s = 0.f, s2 = 0.f;
    for (int r = blockIdx.x; r < n; r += gridDim.x) {
        float v = bf2f(src[(size_t)r * 128 + cc]);
        s += v; s2 += v * v;
    }
    atomicAdd(&sums[c], s);
    atomicAdd(&sumsq[c], s2);
}

__global__ void k_bnfin(const float* __restrict__ sums, const float* __restrict__ sumsq,
                        const float* __restrict__ g, const float* __restrict__ bb,
                        float* __restrict__ scale, float* __restrict__ shift,
                        int cat, float invn)
{
    int c = threadIdx.x;
    if (c >= cat) return;
    float mu  = sums[c] * invn;
    float var = sumsq[c] * invn - mu * mu;
    float sc  = g[c] * rsqrtf(var + 1e-5f);
    scale[c] = sc;
    shift[c] = bb[c] - mu * sc;
}

__global__ void k_bnapply(unsigned short* __restrict__ p0, unsigned short* __restrict__ p1,
                          unsigned short* __restrict__ p2,
                          const float* __restrict__ scale, const float* __restrict__ shift,
                          int n)
{
    int c = threadIdx.x;              // 384
    int cc = c & 127;
    int pi = c >> 7;
    unsigned short* src = (pi == 0) ? p0 : ((pi == 1) ? p1 : p2);
    float sc = scale[c], sh = shift[c];
    for (int r = blockIdx.x; r < n; r += gridDim.x) {
        size_t idx = (size_t)r * 128 + cc;
        float v = bf2f(src[idx]) * sc + sh;
        src[idx] = f2bf(fmaxf(v, 0.0f));
    }
}

// Diagnostic: if workspace is too small, surface ws_size (MB) via d_out.
__global__ void k_diag(float* out, float val, int n) {
    int i = blockIdx.x * blockDim.x + threadIdx.x;
    if (i < n) out[i] = val;
}

// ---------------------------------------------------------------------------
extern "C" void kernel_launch(void* const* d_in, const int* in_sizes, int n_in,
                              void* d_out, int out_size, void* d_ws, size_t ws_size,
                              hipStream_t stream)
{
    const float* x    = (const float*)d_in[0];
    const void*  ei   = d_in[1];
    const float* W0   = (const float*)d_in[2];
    const float* b0   = (const float*)d_in[3];
    const float* W1   = (const float*)d_in[4];
    const float* b1   = (const float*)d_in[5];
    const float* W2   = (const float*)d_in[6];
    const float* b2   = (const float*)d_in[7];
    const float* bn0g = (const float*)d_in[8];
    const float* bn0b = (const float*)d_in[9];
    const float* bn1g = (const float*)d_in[10];
    const float* bn1b = (const float*)d_in[11];
    const float* fpW  = (const float*)d_in[12];
    const float* fpb  = (const float*)d_in[13];
    float* out = (float*)d_out;

    const int N    = in_sizes[0] / IN_C;
    const int twoE = in_sizes[1];
    const int E    = twoE / 2;

    // ---- workspace carve (~184 MB; budget 256 MiB) ----
    char* p = (char*)d_ws;
    auto alloc = [&](size_t bytes) -> char* {
        char* r = p; p += (bytes + 255) & ~(size_t)255; return r;
    };
    // 6 contiguous N x 128 bf16 units; u1|u2 and u2-internal interleaving used.
    unsigned short* u0 = (unsigned short*)alloc((size_t)6 * N * 128 * 2);
    unsigned short* u1 = u0 + (size_t)1 * N * 128;
    unsigned short* u2 = u0 + (size_t)2 * N * 128;
    unsigned short* u3 = u0 + (size_t)3 * N * 128;
    unsigned short* u4 = u0 + (size_t)4 * N * 128;
    unsigned short* u5 = u0 + (size_t)5 * N * 128;
    unsigned short* Wt0 = (unsigned short*)alloc((size_t)3 * 128 * 128 * 2);
    unsigned short* Wt1 = (unsigned short*)alloc((size_t)3 * 384 * 128 * 2);
    unsigned short* Wt2 = (unsigned short*)alloc((size_t)3 * 384 * 64 * 2);
    unsigned short* WtF = (unsigned short*)alloc((size_t)192 * 64 * 2);
    float* dinv  = (float*)alloc((size_t)N * 4);
    int2*  ew    = (int2*)alloc((size_t)E * 8);
    float* sums  = (float*)alloc(2 * 384 * 4);
    float* sumsq = sums + 384;
    float* scale = (float*)alloc(384 * 4);
    float* shift = (float*)alloc(384 * 4);
    int* deg     = (int*)alloc((size_t)N * 4);
    int* base    = (int*)alloc((size_t)N * 4);
    int* cursor  = (int*)alloc((size_t)N * 4);
    int* eint    = (int*)alloc((size_t)twoE * 4);
    int* counter = (int*)alloc(4);
    int* flag    = (int*)alloc(4);

    size_t required = (size_t)(p - (char*)d_ws);
    if (required > ws_size) {
        k_diag<<<(out_size + 255) / 256, 256, 0, stream>>>(
            out, (float)(ws_size >> 20), out_size);
        return;
    }

    const int T = 256;
    dim3 spmm_blk(64, 4);
    int  spmm_grid = (N + 3) / 4;
    int  gx = (N + 127) / 128;

    // ---- weight prep + input cast ----
    k_wprep<<<dim3((128 * 128 + 255) / 256, 3), T, 0, stream>>>(W0, Wt0, 128, 128);
    k_wprep<<<dim3((384 * 128 + 255) / 256, 3), T, 0, stream>>>(W1, Wt1, 384, 128);
    k_wprep<<<dim3((384 * 64  + 255) / 256, 3), T, 0, stream>>>(W2, Wt2, 384, 64);
    k_wprep<<<dim3((192 * 64  + 255) / 256, 1), T, 0, stream>>>(fpW, WtF, 192, 64);
    unsigned short* Xb = u3;
    k_cast4<<<((N * 128 / 4) + 255) / 256, T, 0, stream>>>(x, Xb, N * 128 / 4);

    // ---- graph build ----
    hipMemsetAsync(deg, 0, (size_t)N * 4, stream);
    hipMemsetAsync(counter, 0, 4, stream);
    k_detect<<<1, 64, 0, stream>>>((const long long*)ei, N, flag);
    k_cvt_hist<<<(twoE + T - 1) / T, T, 0, stream>>>(ei, twoE, E, flag, eint, deg, N);
    k_dinv<<<(N + T - 1) / T, T, 0, stream>>>(deg, dinv, N);
    k_alloc<<<(N + T - 1) / T, T, 0, stream>>>(deg, base, cursor, counter, N);
    k_scatter<<<(E + T - 1) / T, T, 0, stream>>>(eint, E, dinv, N, cursor, ew);

    // ---- layer 0: Xb(u3) -> G0:u0 (plain), [G1|G2] interleaved in (u1,u2) ----
    k_gemm<128, true><<<dim3(gx, 3), T, 0, stream>>>(Xb, Xb, Xb, 128, N, 128,
        Wt0, b0, u0, 128, u1, 256, u1 + 128, 256, nullptr, 0);
    // dual: gather [G1|G2] -> H1:u4, T:u5 ; single: T -> H2:u3
    k_spmm2i<128><<<spmm_grid, spmm_blk, 0, stream>>>(u1, u4, u5, base, deg, ew, N);
    k_spmm<2><<<spmm_grid, spmm_blk, 0, stream>>>(u5, u3, 128, base, deg, ew, N);
    hipMemsetAsync(sums, 0, 2 * 384 * 4, stream);
    k_bnstats<<<2048, 384, 0, stream>>>(u0, u4, u3, sums, sumsq, N);
    k_bnfin<<<1, 384, 0, stream>>>(sums, sumsq, bn0g, bn0b, scale, shift, 384, 1.0f / N);
    k_bnapply<<<2048, 384, 0, stream>>>(u0, u4, u3, scale, shift, N);
    // layer-0 output: (u0, u4, u3)

    // ---- layer 1: (u0,u4,u3) -> G0':u5, [G1'|G2'] in (u1,u2) ----
    k_gemm<128, true><<<dim3(gx, 3), T, 0, stream>>>(u0, u4, u3, 128, N, 384,
        Wt1, b1, u5, 128, u1, 256, u1 + 128, 256, nullptr, 0);
    // dual: -> H1':u0, T':u4 ; single: T' -> H2':u3
    k_spmm2i<128><<<spmm_grid, spmm_blk, 0, stream>>>(u1, u0, u4, base, deg, ew, N);
    k_spmm<2><<<spmm_grid, spmm_blk, 0, stream>>>(u4, u3, 128, base, deg, ew, N);
    hipMemsetAsync(sums, 0, 2 * 384 * 4, stream);
    k_bnstats<<<2048, 384, 0, stream>>>(u5, u0, u3, sums, sumsq, N);
    k_bnfin<<<1, 384, 0, stream>>>(sums, sumsq, bn1g, bn1b, scale, shift, 384, 1.0f / N);
    k_bnapply<<<2048, 384, 0, stream>>>(u5, u0, u3, scale, shift, N);
    // layer-1 output: (u5, u0, u3)

    // ---- layer 2: (u5,u0,u3) -> L0:u1 (N x 64), [L1|L2] interleaved in u2 ----
    k_gemm<64, true><<<dim3(gx, 3), T, 0, stream>>>(u5, u0, u3, 128, N, 384,
        Wt2, b2, u1, 64, u2, 128, u2 + 64, 128, nullptr, 0);
    // dual: -> H1f:u4[0:N*64], T2:u4[N*64:] ; single: T2 -> H2f:u5[0:N*64]
    k_spmm2i<64><<<spmm_grid, spmm_blk, 0, stream>>>(u2, u4, u4 + (size_t)N * 64,
                                                     base, deg, ew, N);
    k_spmm<1><<<spmm_grid, spmm_blk, 0, stream>>>(u4 + (size_t)N * 64, u5, 64,
                                                  base, deg, ew, N);

    // ---- final projection: out = concat(u1, u4, u5)(N x 192) @ fpW + fpb ----
    k_gemm<64, false><<<dim3(gx, 1), T, 0, stream>>>(u1, u4, u5, 64, N, 192,
        WtF, fpb, nullptr, 0, nullptr, 0, nullptr, 0, out, 64);
}